// Round 14
// baseline (199.561 us; speedup 1.0000x reference)
//
#include <hip/hip_runtime.h>
#include <hip/hip_bf16.h>

#define NB 4
#define PSEQ 4096
#define DK 64
#define DV 256

typedef __attribute__((ext_vector_type(8))) short short8;
typedef __attribute__((ext_vector_type(16))) float f32x16;
typedef __attribute__((ext_vector_type(4))) unsigned int uint4v;

__device__ __forceinline__ float bf2f(unsigned short u) {
    union { unsigned int i; float f; } v; v.i = ((unsigned int)u) << 16; return v.f;
}
__device__ __forceinline__ unsigned short f2bf(float f) {
    union { float f; unsigned int i; } v; v.f = f;
    return (unsigned short)((v.i + 0x7fffu + ((v.i >> 16) & 1u)) >> 16);
}

// un-reorderable 16B global load: volatile asm, "=v" dest live from issue.
// Caller must s_waitcnt vmcnt(N) (+sched_barrier) before use.
__device__ __forceinline__ short8 gload16(const void* p) {
    short8 r;
    asm volatile("global_load_dwordx4 %0, %1, off"
                 : "=v"(r) : "v"(p) : "memory");
    return r;
}

// ---- prep (r10 verbatim): Q hi/lo, K fragment-pack, W->bf16, V^T-pack ----
//   Kp[n][g(128)][d(4)][lane(64)][8bf16]  : key g*32+l31, dk d*16+hi*8..+8
//   Vp[n][g(128)][c32(8)][slot(2)][lane]  : ch c32*32+l31, key g*32+slot*16+hi*8..+8
__global__ __launch_bounds__(256) void prep_all(
    const float* __restrict__ q, const float* __restrict__ k,
    const float* __restrict__ wfc, const float* __restrict__ v,
    unsigned short* __restrict__ Qh, unsigned short* __restrict__ Ql,
    unsigned short* __restrict__ Kp,
    unsigned short* __restrict__ Wb, unsigned short* __restrict__ Vp) {
    __shared__ float tile[64][65];
    const int b = blockIdx.x, tid = threadIdx.x;
    if (b < 1024) {                       // Q hi/lo split
        const int i = (b * 256 + tid) * 4;
        float4 x = *reinterpret_cast<const float4*>(q + i);
        ushort4 h, l;
        h.x = f2bf(x.x); l.x = f2bf(x.x - bf2f(h.x));
        h.y = f2bf(x.y); l.y = f2bf(x.y - bf2f(h.y));
        h.z = f2bf(x.z); l.z = f2bf(x.z - bf2f(h.z));
        h.w = f2bf(x.w); l.w = f2bf(x.w - bf2f(h.w));
        *reinterpret_cast<ushort4*>(Qh + i) = h;
        *reinterpret_cast<ushort4*>(Ql + i) = l;
    } else if (b < 1536) {                // K fragment-pack (512 blocks: n x g)
        const int idx = b - 1024;
        const int n = idx >> 7, g = idx & 127;
        const int d = tid >> 6, lane = tid & 63;
        const int l31 = lane & 31, hi = lane >> 5;
        const float* src = k + ((size_t)(n * PSEQ + g * 32 + l31)) * DK + d * 16 + hi * 8;
        float x[8];
        *reinterpret_cast<float4*>(&x[0]) = *reinterpret_cast<const float4*>(src);
        *reinterpret_cast<float4*>(&x[4]) = *reinterpret_cast<const float4*>(src + 4);
        short8 o;
#pragma unroll
        for (int j = 0; j < 8; ++j) o[j] = (short)f2bf(x[j]);
        *reinterpret_cast<short8*>(
            Kp + (((size_t)n * 512 + g * 4 + d) * 64 + lane) * 8) = o;
    } else if (b < 1600) {                // W -> bf16
        const int i = ((b - 1536) * 256 + tid) * 4;
        float4 x = *reinterpret_cast<const float4*>(wfc + i);
        ushort4 h;
        h.x = f2bf(x.x); h.y = f2bf(x.y); h.z = f2bf(x.z); h.w = f2bf(x.w);
        *reinterpret_cast<ushort4*>(Wb + i) = h;
    } else {                              // V transpose + fragment-pack
        const int vtid = b - 1600;
        const int k0 = (vtid & 63) * 64, c0 = ((vtid >> 6) & 3) * 64, n = vtid >> 8;
        const int gb = (vtid & 63) * 2;         // g base (key/32)
        const int cb = ((vtid >> 6) & 3) * 2;   // c32 base (ch/32)
        const float* vn = v + (size_t)n * PSEQ * DV;
        const int tx = tid & 15, ty = tid >> 4;
#pragma unroll
        for (int rep = 0; rep < 4; ++rep) {
            int r = ty + rep * 16;
            float4 d = *reinterpret_cast<const float4*>(vn + (size_t)(k0 + r) * DV + c0 + tx * 4);
            tile[r][tx * 4 + 0] = d.x; tile[r][tx * 4 + 1] = d.y;
            tile[r][tx * 4 + 2] = d.z; tile[r][tx * 4 + 3] = d.w;
        }
        __syncthreads();
#pragma unroll
        for (int uu = 0; uu < 2; ++uu) {
            const int u = tid * 2 + uu;
            const int lane = u & 63;
            const int slot = (u >> 6) & 1;
            const int c32l = (u >> 7) & 1;
            const int gl   = (u >> 8) & 1;
            const int l31 = lane & 31, hi = lane >> 5;
            const int keyl = gl * 32 + slot * 16 + hi * 8;
            const int chl = c32l * 32 + l31;
            short8 o;
#pragma unroll
            for (int j = 0; j < 8; ++j) o[j] = (short)f2bf(tile[keyl + j][chl]);
            *reinterpret_cast<short8*>(
                Vp + ((((size_t)n * 128 + gb + gl) * 8 + cb + c32l) * 2 + slot) * 512
                   + lane * 8) = o;
        }
    }
}

// ---- barrier-free attention v7b: 64-q blocks for L2-request reuse ----
// r13 crashed: __launch_bounds__(512,4) capped unified regs at 128 but the
// asm-forced live set (~160 VGPR + 64 acc) is infeasible -> launch abort.
// r14 = r13 with the ONLY change being a feasible bound (512,2), restoring
// r12's proven ~168-reg budget. Theory under test: the two waves with equal
// kq and different qh have IDENTICAL K/V load streams on the same CU; per
// tile the pair touches 12KB vs 32KB L1, so with <2 tiles of drift the
// second wave's requests are L1 hits -> the L2 request/traffic stream
// (the only lever that ever moved this kernel, r10) is ~halved.
__global__ __launch_bounds__(512, 2) void attn_wave(
    const unsigned short* __restrict__ Kp,
    const unsigned short* __restrict__ Qh,
    const unsigned short* __restrict__ Ql,
    const unsigned short* __restrict__ Vp,
    const unsigned short* __restrict__ Wg,
    const float* __restrict__ Bg,
    float* __restrict__ Og)
{
    __shared__ float Of32[64][128];          // 32 KB f32 O accumulator (this ch-half)
    __shared__ unsigned short Omrg[64][132]; // 16.9 KB bf16
    __shared__ float Lsh[64];

    const int tid = threadIdx.x;
    const int w = tid >> 6;          // 8 waves
    const int kq = w & 3;            // key-quarter: keys [kq*1024,+1024)
    const int qh = w >> 2;           // q-half: rows [qh*32,+32) of the block
    const int lane = tid & 63;
    const int l31 = lane & 31;
    const int hi = lane >> 5;

    const int id = blockIdx.x;
    const int n   = (id & 7) >> 1;           // XCD locality
    const int chb = id & 1;                  // channel half: [chb*128, +128)
    const int q0  = (id >> 3) * 64;          // 0..4032

    if (tid < 64) Lsh[tid] = 0.f;
    __syncthreads();

    const unsigned short* Kpn = Kp + (size_t)n * 512 * 512;
    const unsigned short* Vpn = Vp + (size_t)n * 128 * 8 * 2 * 512;

    // Q B-fragments: col = q0+qh*32+l31, dk-slot d -> k = d*16 + hi*8 + j
    short8 qhf[4], qlf[4];
#pragma unroll
    for (int d = 0; d < 4; ++d) {
        const size_t a = ((size_t)n * PSEQ + q0 + qh * 32 + l31) * DK + d * 16 + hi * 8;
        qhf[d] = *reinterpret_cast<const short8*>(Qh + a);
        qlf[d] = *reinterpret_cast<const short8*>(Ql + a);
    }

    const f32x16 Z16 = {0.f,0.f,0.f,0.f, 0.f,0.f,0.f,0.f,
                        0.f,0.f,0.f,0.f, 0.f,0.f,0.f,0.f};
    f32x16 oacc[4];
#pragma unroll
    for (int ct = 0; ct < 4; ++ct) oacc[ct] = Z16;

    float lsum = 0.f;
    const float SC = 0.125f * 1.44269504088896340736f;

    short8 vv[8];   // single V buffer, refilled at tile end for tile kt+1

    auto issueK = [&](int kt, short8 (&kf)[4]) {
        const int g = kq * 32 + (kt < 31 ? kt : 31);
#pragma unroll
        for (int d = 0; d < 4; ++d)
            kf[d] = gload16(Kpn + ((size_t)(g * 4 + d) * 64 + lane) * 8);
    };
    auto issueV = [&](int kt) {
        const int g = kq * 32 + (kt < 31 ? kt : 31);
#pragma unroll
        for (int ct = 0; ct < 4; ++ct) {
            const size_t vb = (((size_t)g * 8 + chb * 4 + ct) * 2) * 512;
            vv[ct]     = gload16(Vpn + vb + lane * 8);
            vv[4 + ct] = gload16(Vpn + vb + 512 + lane * 8);
        }
    };

    // TILE(kt): kfC holds K(kt); issueK(kt+2) overwrites kfC after QK reads.
    auto TILE = [&](int kt, short8 (&kfC)[4]) {
        // S^T = K·Q (+ error-feedback lo-term); K(kt) ready via prev vmcnt(4)
        f32x16 s = Z16;
        __builtin_amdgcn_s_setprio(1);
#pragma unroll
        for (int d = 0; d < 4; ++d)
            s = __builtin_amdgcn_mfma_f32_32x32x16_bf16(kfC[d], qhf[d], s, 0, 0, 0);
#pragma unroll
        for (int d = 0; d < 4; ++d)
            s = __builtin_amdgcn_mfma_f32_32x32x16_bf16(kfC[d], qlf[d], s, 0, 0, 0);
        __builtin_amdgcn_s_setprio(0);

        // K(kt+2) into the buffer QK just consumed (WAR-safe)
        issueK(kt + 2, kfC);

        // softmax: fused exp2 -> cvt_pk, then permlane rebuild of A-fragments
        unsigned int pk[8];
        float lacc = 0.f;
#pragma unroll
        for (int j = 0; j < 8; ++j) {
            float p0 = exp2f(s[2 * j] * SC);
            float p1 = exp2f(s[2 * j + 1] * SC);
            lacc += p0 + p1;
            asm("v_cvt_pk_bf16_f32 %0, %1, %2" : "=v"(pk[j]) : "v"(p0), "v"(p1));
        }
        lsum += lacc;
        asm volatile("v_permlane32_swap_b32 %0, %1" : "+v"(pk[0]), "+v"(pk[2]));
        asm volatile("v_permlane32_swap_b32 %0, %1" : "+v"(pk[1]), "+v"(pk[3]));
        asm volatile("v_permlane32_swap_b32 %0, %1" : "+v"(pk[4]), "+v"(pk[6]));
        asm volatile("v_permlane32_swap_b32 %0, %1" : "+v"(pk[5]), "+v"(pk[7]));
        union { uint4v u; short8 s8; } cvt0, cvt1;
        cvt0.u = (uint4v){pk[0], pk[1], pk[2], pk[3]};
        cvt1.u = (uint4v){pk[4], pk[5], pk[6], pk[7]};
        const short8 pa0 = cvt0.s8, pa1 = cvt1.s8;

        // the ONLY wait: V(kt) (issued end of prev tile) + K(kt+1) done;
        // K(kt+2) stays in flight.
        asm volatile("s_waitcnt vmcnt(4)" ::: "memory");
        __builtin_amdgcn_sched_barrier(0);

        __builtin_amdgcn_s_setprio(1);
#pragma unroll
        for (int ct = 0; ct < 4; ++ct)
            oacc[ct] = __builtin_amdgcn_mfma_f32_32x32x16_bf16(pa0, vv[ct], oacc[ct], 0, 0, 0);
#pragma unroll
        for (int ct = 0; ct < 4; ++ct)
            oacc[ct] = __builtin_amdgcn_mfma_f32_32x32x16_bf16(pa1, vv[4 + ct], oacc[ct], 0, 0, 0);
        __builtin_amdgcn_s_setprio(0);

        // V for next tile into the just-freed vv regs
        issueV(kt + 1);
    };

    // prologue: K(0),K(1),V(0) in flight; wait K(0) only (K1,V0 = 12 remain)
    short8 kfA[4], kfB[4];
    issueK(0, kfA);
    issueK(1, kfB);
    issueV(0);
    asm volatile("s_waitcnt vmcnt(12)" ::: "memory");
    __builtin_amdgcn_sched_barrier(0);

#pragma unroll 1
    for (int kt = 0; kt < 32; kt += 2) {
        TILE(kt, kfA);
        TILE(kt + 1, kfB);
    }
    asm volatile("s_waitcnt vmcnt(0)" ::: "memory");   // drain tail loads

    // ---- block-end merge: per q-half, 4 key-quarter partials ----
    lsum += __shfl_xor(lsum, 32, 64);
    if (lane < 32) atomicAdd(&Lsh[qh * 32 + l31], lsum);

    if (kq == 0) {
#pragma unroll
        for (int ct = 0; ct < 4; ++ct)
#pragma unroll
            for (int r = 0; r < 16; ++r) {
                const int row = qh * 32 + (r & 3) + 8 * (r >> 2) + 4 * hi;
                Of32[row][ct * 32 + l31] = oacc[ct][r];
            }
    }
    __syncthreads();
    if (kq == 1) {
#pragma unroll
        for (int ct = 0; ct < 4; ++ct)
#pragma unroll
            for (int r = 0; r < 16; ++r) {
                const int row = qh * 32 + (r & 3) + 8 * (r >> 2) + 4 * hi;
                Of32[row][ct * 32 + l31] += oacc[ct][r];
            }
    }
    __syncthreads();
    if (kq == 2) {
#pragma unroll
        for (int ct = 0; ct < 4; ++ct)
#pragma unroll
            for (int r = 0; r < 16; ++r) {
                const int row = qh * 32 + (r & 3) + 8 * (r >> 2) + 4 * hi;
                Of32[row][ct * 32 + l31] += oacc[ct][r];
            }
    }
    __syncthreads();
    if (kq == 3) {
#pragma unroll
        for (int ct = 0; ct < 4; ++ct)
#pragma unroll
            for (int r = 0; r < 16; ++r) {
                const int row = qh * 32 + (r & 3) + 8 * (r >> 2) + 4 * hi;
                Of32[row][ct * 32 + l31] += oacc[ct][r];
            }
    }
    __syncthreads();

    // ---- normalize -> bf16 Omrg (64 rows x 128 ch, 16 f32/thread) ----
    {
        const int row = tid >> 3;
        const int col0 = (tid & 7) * 16;
        const float il = 1.0f / Lsh[row];
#pragma unroll
        for (int j = 0; j < 4; ++j) {
            float4 xv = *reinterpret_cast<const float4*>(&Of32[row][col0 + j * 4]);
            ushort4 o;
            o.x = f2bf(xv.x * il); o.y = f2bf(xv.y * il);
            o.z = f2bf(xv.z * il); o.w = f2bf(xv.w * il);
            *reinterpret_cast<ushort4*>(&Omrg[row][col0 + j * 4]) = o;
        }
    }
    __syncthreads();

    // ---- partial fc over this ch-half: wave w -> oc [w*32,+32), rows 0..63 ----
    f32x16 fa[2];
    fa[0] = Z16; fa[1] = Z16;
    short8 wf[8];
#pragma unroll
    for (int slot = 0; slot < 8; ++slot)
        wf[slot] = *reinterpret_cast<const short8*>(
            Wg + (size_t)(w * 32 + l31) * DV + chb * 128 + slot * 16 + hi * 8);
#pragma unroll
    for (int rt = 0; rt < 2; ++rt) {
#pragma unroll
        for (int slot = 0; slot < 8; ++slot) {
            short8 af = *reinterpret_cast<const short8*>(
                &Omrg[rt * 32 + l31][slot * 16 + hi * 8]);
            fa[rt] = __builtin_amdgcn_mfma_f32_32x32x16_bf16(af, wf[slot], fa[rt], 0, 0, 0);
        }
    }
    {
        const float b0 = chb == 0 ? Bg[w * 32 + l31] : 0.f;
#pragma unroll
        for (int rt = 0; rt < 2; ++rt)
#pragma unroll
            for (int r = 0; r < 16; ++r) {
                const int row = rt * 32 + (r & 3) + 8 * (r >> 2) + 4 * hi;
                const size_t orow = ((size_t)n * PSEQ + q0 + row) * DV;
                atomicAdd(&Og[orow + w * 32 + l31], fa[rt][r] + b0);
            }
    }
}

extern "C" void kernel_launch(void* const* d_in, const int* in_sizes, int n_in,
                              void* d_out, int out_size, void* d_ws, size_t ws_size,
                              hipStream_t stream) {
    const float* k_src = (const float*)d_in[0];
    const float* v_src = (const float*)d_in[1];
    const float* q_tgr = (const float*)d_in[2];
    const float* W_fc  = (const float*)d_in[3];
    const float* b_fc  = (const float*)d_in[4];
    float* out = (float*)d_out;

    char* wsb = (char*)d_ws;
    unsigned short* Vp = (unsigned short*)(wsb);              //  8 MB packed V
    unsigned short* Qh = (unsigned short*)(wsb + 8388608);    //  2 MB
    unsigned short* Ql = (unsigned short*)(wsb + 10485760);   //  2 MB
    unsigned short* Kp = (unsigned short*)(wsb + 12582912);   //  2 MB packed K
    unsigned short* Wb = (unsigned short*)(wsb + 14680064);   //  128 KB

    prep_all<<<2624, 256, 0, stream>>>(q_tgr, k_src, W_fc, v_src,
                                       Qh, Ql, Kp, Wb, Vp);
    hipMemsetAsync(d_out, 0, (size_t)out_size, stream);
    attn_wave<<<512, 512, 0, stream>>>(Kp, Qh, Ql, Vp, Wb, b_fc, out);
}

// Round 15
// 178.515 us; speedup vs baseline: 1.1179x; 1.1179x over previous
//
#include <hip/hip_runtime.h>
#include <hip/hip_bf16.h>

#define NB 4
#define PSEQ 4096
#define DK 64
#define DV 256

typedef __attribute__((ext_vector_type(8))) short short8;
typedef __attribute__((ext_vector_type(16))) float f32x16;
typedef __attribute__((ext_vector_type(4))) unsigned int uint4v;

__device__ __forceinline__ float bf2f(unsigned short u) {
    union { unsigned int i; float f; } v; v.i = ((unsigned int)u) << 16; return v.f;
}
__device__ __forceinline__ unsigned short f2bf(float f) {
    union { float f; unsigned int i; } v; v.f = f;
    return (unsigned short)((v.i + 0x7fffu + ((v.i >> 16) & 1u)) >> 16);
}

// un-reorderable 16B global load: volatile asm, "=v" dest live from issue.
// Caller must s_waitcnt vmcnt(N) (+sched_barrier) before use.
__device__ __forceinline__ short8 gload16(const void* p) {
    short8 r;
    asm volatile("global_load_dwordx4 %0, %1, off"
                 : "=v"(r) : "v"(p) : "memory");
    return r;
}

// ---- prep: Q hi/lo, K fragment-pack, W->bf16, V transpose+fragment-pack ----
// K and V stored in FRAGMENT-ORDER so each main-loop wave load is a
// contiguous 1KB read (8 fully-used 128B lines). Direct fragment loads
// strided 128B (K) / 8KB (V) across lanes cost 32 quarter-used lines per
// instr (~6.3GB L2 line traffic = the entire 207us attn wall pre-r10);
// packing cut it 4x -> 207us -> 114us, the one structural win of the session.
//   Kp[n][g(128)][d(4)][lane(64)][8bf16]  : key g*32+l31, dk d*16+hi*8..+8
//   Vp[n][g(128)][c32(8)][slot(2)][lane]  : ch c32*32+l31, key g*32+slot*16+hi*8..+8
__global__ __launch_bounds__(256) void prep_all(
    const float* __restrict__ q, const float* __restrict__ k,
    const float* __restrict__ wfc, const float* __restrict__ v,
    unsigned short* __restrict__ Qh, unsigned short* __restrict__ Ql,
    unsigned short* __restrict__ Kp,
    unsigned short* __restrict__ Wb, unsigned short* __restrict__ Vp) {
    __shared__ float tile[64][65];
    const int b = blockIdx.x, tid = threadIdx.x;
    if (b < 1024) {                       // Q hi/lo split
        const int i = (b * 256 + tid) * 4;
        float4 x = *reinterpret_cast<const float4*>(q + i);
        ushort4 h, l;
        h.x = f2bf(x.x); l.x = f2bf(x.x - bf2f(h.x));
        h.y = f2bf(x.y); l.y = f2bf(x.y - bf2f(h.y));
        h.z = f2bf(x.z); l.z = f2bf(x.z - bf2f(h.z));
        h.w = f2bf(x.w); l.w = f2bf(x.w - bf2f(h.w));
        *reinterpret_cast<ushort4*>(Qh + i) = h;
        *reinterpret_cast<ushort4*>(Ql + i) = l;
    } else if (b < 1536) {                // K fragment-pack (512 blocks: n x g)
        const int idx = b - 1024;
        const int n = idx >> 7, g = idx & 127;
        const int d = tid >> 6, lane = tid & 63;
        const int l31 = lane & 31, hi = lane >> 5;
        const float* src = k + ((size_t)(n * PSEQ + g * 32 + l31)) * DK + d * 16 + hi * 8;
        float x[8];
        *reinterpret_cast<float4*>(&x[0]) = *reinterpret_cast<const float4*>(src);
        *reinterpret_cast<float4*>(&x[4]) = *reinterpret_cast<const float4*>(src + 4);
        short8 o;
#pragma unroll
        for (int j = 0; j < 8; ++j) o[j] = (short)f2bf(x[j]);
        *reinterpret_cast<short8*>(
            Kp + (((size_t)n * 512 + g * 4 + d) * 64 + lane) * 8) = o;
    } else if (b < 1600) {                // W -> bf16
        const int i = ((b - 1536) * 256 + tid) * 4;
        float4 x = *reinterpret_cast<const float4*>(wfc + i);
        ushort4 h;
        h.x = f2bf(x.x); h.y = f2bf(x.y); h.z = f2bf(x.z); h.w = f2bf(x.w);
        *reinterpret_cast<ushort4*>(Wb + i) = h;
    } else {                              // V transpose + fragment-pack
        const int vtid = b - 1600;
        const int k0 = (vtid & 63) * 64, c0 = ((vtid >> 6) & 3) * 64, n = vtid >> 8;
        const int gb = (vtid & 63) * 2;         // g base (key/32)
        const int cb = ((vtid >> 6) & 3) * 2;   // c32 base (ch/32)
        const float* vn = v + (size_t)n * PSEQ * DV;
        const int tx = tid & 15, ty = tid >> 4;
#pragma unroll
        for (int rep = 0; rep < 4; ++rep) {
            int r = ty + rep * 16;
            float4 d = *reinterpret_cast<const float4*>(vn + (size_t)(k0 + r) * DV + c0 + tx * 4);
            tile[r][tx * 4 + 0] = d.x; tile[r][tx * 4 + 1] = d.y;
            tile[r][tx * 4 + 2] = d.z; tile[r][tx * 4 + 3] = d.w;
        }
        __syncthreads();
        // packed write: 512 16B-units; thread t -> units 2t, 2t+1
#pragma unroll
        for (int uu = 0; uu < 2; ++uu) {
            const int u = tid * 2 + uu;
            const int lane = u & 63;
            const int slot = (u >> 6) & 1;
            const int c32l = (u >> 7) & 1;
            const int gl   = (u >> 8) & 1;
            const int l31 = lane & 31, hi = lane >> 5;
            const int keyl = gl * 32 + slot * 16 + hi * 8;   // key_local base
            const int chl = c32l * 32 + l31;                 // ch_local
            short8 o;
#pragma unroll
            for (int j = 0; j < 8; ++j) o[j] = (short)f2bf(tile[keyl + j][chl]);
            *reinterpret_cast<short8*>(
                Vp + ((((size_t)n * 128 + gb + gl) * 8 + cb + c32l) * 2 + slot) * 512
                   + lane * 8) = o;
        }
    }
}

// ---- barrier-free attention (session optimum, r10): asm-pipelined,
// fragment-packed loads. Wave = 32 q x 128 ch x 2048 keys; block =
// (key-half kh) x (ch-half ch); main loop has ZERO LDS traffic and ZERO
// barriers. Per 32-key tile: swapped QK^T (mfma32(K,Q), hi+lo Q
// error-feedback) -> in-register softmax (exp2 + v_cvt_pk_bf16_f32 +
// v_permlane32_swap_b32 rebuild of PV A-fragments) -> PV mfma32.
//   TILE(kt): [wait vmcnt(0)] issueV(kt) | QK(kfC) | issueK(kt+1->kfN) |
//             softmax | [wait vmcnt(4)] | PV
// Session evidence: per-SIMD tile-slot is ~2100cy in EVERY config tried
// (2 or 4 waves/SIMD, 1- or 2-wait, shared or private streams); the only
// lever that moved the wall was L2 line-request count (packing, 1.8x).
__global__ __launch_bounds__(256, 2) void attn_wave(
    const unsigned short* __restrict__ Kp,
    const unsigned short* __restrict__ Qh,
    const unsigned short* __restrict__ Ql,
    const unsigned short* __restrict__ Vp,
    const unsigned short* __restrict__ Wg,
    const float* __restrict__ Bg,
    float* __restrict__ Og)
{
    __shared__ float Of32[32][256];          // 32 KB f32 O accumulator
    __shared__ unsigned short Omrg[32][260]; // 16.25 KB bf16
    __shared__ float Lsh[32];

    const int tid = threadIdx.x;
    const int w = tid >> 6;
    const int lane = tid & 63;
    const int l31 = lane & 31;
    const int hi = lane >> 5;
    const int kh = w >> 1;           // key half: keys [kh*2048, +2048)
    const int ch = w & 1;            // channel half: [ch*128, +128)

    const int id = blockIdx.x;
    const int n = (id & 7) >> 1;                     // XCD-pair locality per batch
    const int q0 = ((id >> 3) * 2 + (id & 1)) * 32;  // bijective 0..4064

    if (tid < 32) Lsh[tid] = 0.f;
    __syncthreads();

    const unsigned short* Kpn = Kp + (size_t)n * 512 * 512;     // n*512KB/2
    const unsigned short* Vpn = Vp + (size_t)n * 128 * 8 * 2 * 512;

    // Q B-fragments: col = q0+l31, dk-slot d -> k = d*16 + hi*8 + j
    short8 qhf[4], qlf[4];
#pragma unroll
    for (int d = 0; d < 4; ++d) {
        const size_t a = ((size_t)n * PSEQ + q0 + l31) * DK + d * 16 + hi * 8;
        qhf[d] = *reinterpret_cast<const short8*>(Qh + a);
        qlf[d] = *reinterpret_cast<const short8*>(Ql + a);
    }

    const f32x16 Z16 = {0.f,0.f,0.f,0.f, 0.f,0.f,0.f,0.f,
                        0.f,0.f,0.f,0.f, 0.f,0.f,0.f,0.f};
    f32x16 oacc[4];
#pragma unroll
    for (int ct = 0; ct < 4; ++ct) oacc[ct] = Z16;

    float lsum = 0.f;
    const float SC = 0.125f * 1.44269504088896340736f;

    auto issueK = [&](int kt, short8 (&kf)[4]) {
        const int g = kh * 64 + kt;
#pragma unroll
        for (int d = 0; d < 4; ++d)
            kf[d] = gload16(Kpn + ((size_t)(g * 4 + d) * 64 + lane) * 8);
    };

    auto TILE = [&](int kt, short8 (&kfC)[4], short8 (&kfN)[4]) {
        // K(kt) arrived (the only 4 outstanding at entry)
        asm volatile("s_waitcnt vmcnt(0)" ::: "memory");
        __builtin_amdgcn_sched_barrier(0);

        const int g = kh * 64 + kt;

        // issue V(kt): 8 contiguous 1KB loads
        short8 vv[8];
#pragma unroll
        for (int ct = 0; ct < 4; ++ct) {
            const size_t vb = (((size_t)g * 8 + ch * 4 + ct) * 2) * 512;
            vv[ct]     = gload16(Vpn + vb + lane * 8);
            vv[4 + ct] = gload16(Vpn + vb + 512 + lane * 8);
        }

        // S^T = K·Q (+ error-feedback lo-term): D col = q = l31, rows = keys
        f32x16 s = Z16;
        __builtin_amdgcn_s_setprio(1);
#pragma unroll
        for (int d = 0; d < 4; ++d)
            s = __builtin_amdgcn_mfma_f32_32x32x16_bf16(kfC[d], qhf[d], s, 0, 0, 0);
#pragma unroll
        for (int d = 0; d < 4; ++d)
            s = __builtin_amdgcn_mfma_f32_32x32x16_bf16(kfC[d], qlf[d], s, 0, 0, 0);
        __builtin_amdgcn_s_setprio(0);

        // issue K(kt+1): covered by softmax + PV + loop-around
        issueK(kt < 63 ? kt + 1 : 63, kfN);

        // softmax: fused exp2 -> cvt_pk, then permlane rebuild of A-fragments
        unsigned int pk[8];
        float lacc = 0.f;
#pragma unroll
        for (int j = 0; j < 8; ++j) {
            float p0 = exp2f(s[2 * j] * SC);
            float p1 = exp2f(s[2 * j + 1] * SC);
            lacc += p0 + p1;
            asm("v_cvt_pk_bf16_f32 %0, %1, %2" : "=v"(pk[j]) : "v"(p0), "v"(p1));
        }
        lsum += lacc;
        asm volatile("v_permlane32_swap_b32 %0, %1" : "+v"(pk[0]), "+v"(pk[2]));
        asm volatile("v_permlane32_swap_b32 %0, %1" : "+v"(pk[1]), "+v"(pk[3]));
        asm volatile("v_permlane32_swap_b32 %0, %1" : "+v"(pk[4]), "+v"(pk[6]));
        asm volatile("v_permlane32_swap_b32 %0, %1" : "+v"(pk[5]), "+v"(pk[7]));
        union { uint4v u; short8 s8; } cvt0, cvt1;
        cvt0.u = (uint4v){pk[0], pk[1], pk[2], pk[3]};
        cvt1.u = (uint4v){pk[4], pk[5], pk[6], pk[7]};
        const short8 pa0 = cvt0.s8, pa1 = cvt1.s8;

        // V(kt) arrived (8 oldest of 12); K(kt+1) stays in flight
        asm volatile("s_waitcnt vmcnt(4)" ::: "memory");
        __builtin_amdgcn_sched_barrier(0);

        __builtin_amdgcn_s_setprio(1);
#pragma unroll
        for (int ct = 0; ct < 4; ++ct)
            oacc[ct] = __builtin_amdgcn_mfma_f32_32x32x16_bf16(pa0, vv[ct], oacc[ct], 0, 0, 0);
#pragma unroll
        for (int ct = 0; ct < 4; ++ct)
            oacc[ct] = __builtin_amdgcn_mfma_f32_32x32x16_bf16(pa1, vv[4 + ct], oacc[ct], 0, 0, 0);
        __builtin_amdgcn_s_setprio(0);
    };

    // prologue: establish the 4-outstanding entry invariant
    short8 kfA[4], kfB[4];
    issueK(0, kfA);

#pragma unroll 1
    for (int kt = 0; kt < 64; kt += 2) {
        TILE(kt, kfA, kfB);
        TILE(kt + 1, kfB, kfA);
    }
    asm volatile("s_waitcnt vmcnt(0)" ::: "memory");   // drain dummy K

    // ---- block-end merge (the ONLY cross-wave sync) ----
    lsum += __shfl_xor(lsum, 32, 64);
    if (ch == 0 && lane < 32) atomicAdd(&Lsh[l31], lsum);

    // O merge without atomics: kh=0 stores, sync, kh=1 adds
    const int cb0 = ch * 128;
    if (kh == 0) {
#pragma unroll
        for (int ct = 0; ct < 4; ++ct)
#pragma unroll
            for (int r = 0; r < 16; ++r) {
                const int row = (r & 3) + 8 * (r >> 2) + 4 * hi;
                Of32[row][cb0 + ct * 32 + l31] = oacc[ct][r];
            }
    }
    __syncthreads();
    if (kh == 1) {
#pragma unroll
        for (int ct = 0; ct < 4; ++ct)
#pragma unroll
            for (int r = 0; r < 16; ++r) {
                const int row = (r & 3) + 8 * (r >> 2) + 4 * hi;
                Of32[row][cb0 + ct * 32 + l31] += oacc[ct][r];
            }
    }
    __syncthreads();

    // ---- normalize -> bf16 Omrg ----
    {
        const int row = tid >> 3;
        const int col0 = (tid & 7) * 32;
        const float il = 1.0f / Lsh[row];
#pragma unroll
        for (int j = 0; j < 8; ++j) {
            float4 xv = *reinterpret_cast<const float4*>(&Of32[row][col0 + j * 4]);
            ushort4 o;
            o.x = f2bf(xv.x * il); o.y = f2bf(xv.y * il);
            o.z = f2bf(xv.z * il); o.w = f2bf(xv.w * il);
            *reinterpret_cast<ushort4*>(&Omrg[row][col0 + j * 4]) = o;
        }
    }
    __syncthreads();

    // ---- fused fc: wave w -> out-channels [w*64, +64) ----
    f32x16 fa0 = Z16, fa1 = Z16;
#pragma unroll
    for (int slot = 0; slot < 16; ++slot) {
        short8 af = *reinterpret_cast<const short8*>(&Omrg[l31][slot * 16 + hi * 8]);
        short8 w0 = *reinterpret_cast<const short8*>(
            Wg + (size_t)(w * 64 + l31) * DV + slot * 16 + hi * 8);
        short8 w1 = *reinterpret_cast<const short8*>(
            Wg + (size_t)(w * 64 + 32 + l31) * DV + slot * 16 + hi * 8);
        fa0 = __builtin_amdgcn_mfma_f32_32x32x16_bf16(af, w0, fa0, 0, 0, 0);
        fa1 = __builtin_amdgcn_mfma_f32_32x32x16_bf16(af, w1, fa1, 0, 0, 0);
    }
    {
        const float b0 = Bg[w * 64 + l31], b1 = Bg[w * 64 + 32 + l31];
#pragma unroll
        for (int r = 0; r < 16; ++r) {
            const int row = (r & 3) + 8 * (r >> 2) + 4 * hi;
            const size_t orow = ((size_t)n * PSEQ + q0 + row) * DV;
            Og[orow + w * 64 + l31]      = fa0[r] + b0;
            Og[orow + w * 64 + 32 + l31] = fa1[r] + b1;
        }
    }
}

extern "C" void kernel_launch(void* const* d_in, const int* in_sizes, int n_in,
                              void* d_out, int out_size, void* d_ws, size_t ws_size,
                              hipStream_t stream) {
    const float* k_src = (const float*)d_in[0];
    const float* v_src = (const float*)d_in[1];
    const float* q_tgr = (const float*)d_in[2];
    const float* W_fc  = (const float*)d_in[3];
    const float* b_fc  = (const float*)d_in[4];
    float* out = (float*)d_out;

    char* wsb = (char*)d_ws;
    unsigned short* Vp = (unsigned short*)(wsb);              //  8 MB packed V
    unsigned short* Qh = (unsigned short*)(wsb + 8388608);    //  2 MB
    unsigned short* Ql = (unsigned short*)(wsb + 10485760);   //  2 MB
    unsigned short* Kp = (unsigned short*)(wsb + 12582912);   //  2 MB packed K
    unsigned short* Wb = (unsigned short*)(wsb + 14680064);   //  128 KB

    prep_all<<<2624, 256, 0, stream>>>(q_tgr, k_src, W_fc, v_src,
                                       Qh, Ql, Kp, Wb, Vp);
    attn_wave<<<512, 256, 0, stream>>>(Kp, Qh, Ql, Vp, Wb, b_fc, out);
}